// Round 7
// baseline (86.639 us; speedup 1.0000x reference)
//
#include <hip/hip_runtime.h>
#include <math.h>

typedef float v2f __attribute__((ext_vector_type(2)));

#define NSUP 512
#define DLAT 128
#define DHID 512
#define DIN  64
#define BR   16
#define NTILE 256   // 4096 / BR

// ---------------- prep: transposes + packs + planar support trig + norms ----------------
__global__ __launch_bounds__(512) void prep_kernel(
    const float* __restrict__ x, const float* __restrict__ W1, const float* __restrict__ W2,
    const float* __restrict__ support,
    float* __restrict__ W1T, float* __restrict__ W2T, float* __restrict__ xpack,
    float* __restrict__ scS, float* __restrict__ scC, float* __restrict__ scN,
    float* __restrict__ sn2)
{
    int idx = blockIdx.x * 512 + threadIdx.x;          // 512 x 512 = 262144
    {   // xpack[t][k][r] = x[t*16+r][k]   (writes coalesced)
        int t = idx >> 10, rem = idx & 1023, k = rem >> 4, r = rem & 15;
        xpack[idx] = x[((t << 4) | r) * DIN + k];
    }
    if (idx < DHID * DIN) {                 // W1 [512][64] -> W1T [64][512]
        int c = idx / DIN, k = idx % DIN;
        W1T[k * DHID + c] = W1[idx];
    }
    if (idx < DLAT * DHID) {
        int j = idx / DHID, k = idx % DHID;             // W2 -> W2T
        W2T[k * DLAT + j] = W2[idx];
        int s = idx & (NSUP - 1), i = idx >> 9;         // planar [i][s], writes coalesced
        float v = support[s * DLAT + i];
        scS[idx] = v;
        scC[idx] = cosf(0.5f * v);
        scN[idx] = sinf(0.5f * v);
    }
    if (idx < NSUP) {                       // ||s||^2 via float4
        const float4* sp = (const float4*)(support + idx * DLAT);
        float acc = 0.f;
        #pragma unroll 8
        for (int i4 = 0; i4 < DLAT / 4; i4++) {
            float4 v = sp[i4];
            acc = fmaf(v.x, v.x, fmaf(v.y, v.y, fmaf(v.z, v.z, fmaf(v.w, v.w, acc))));
        }
        sn2[idx] = acc;
    }
}

// ---------------- GEMM1: h = tanh(x @ W1^T + b1)  (s_load broadcast path) ----------------
__global__ __launch_bounds__(512) void gemm1_kernel(
    const float* __restrict__ W1T, const float* __restrict__ b1,
    const float* __restrict__ xpack, float* __restrict__ hpack)
{
    __shared__ float sh[DHID][17];                           // 34.8 KB
    const int t = blockIdx.x;
    const int c = threadIdx.x;
    const float* __restrict__ xr = xpack + t * (DIN * BR);   // uniform base -> s_load

    v2f acc[8];
    #pragma unroll
    for (int q = 0; q < 8; q++) acc[q] = (v2f)(0.f);

    for (int k = 0; k < DIN; k++) {
        float w = W1T[k * DHID + c];
        v2f wv = {w, w};
        const float* xk = xr + k * BR;                       // uniform -> s_load_dwordx16
        #pragma unroll
        for (int q = 0; q < 8; q++) {
            v2f xv = {xk[2 * q], xk[2 * q + 1]};
            acc[q] = __builtin_elementwise_fma(xv, wv, acc[q]);
        }
    }
    float bb = b1[c];
    #pragma unroll
    for (int q = 0; q < 8; q++) {
        sh[c][2 * q]     = tanhf(acc[q].x + bb);
        sh[c][2 * q + 1] = tanhf(acc[q].y + bb);
    }
    __syncthreads();
    float4* hp = (float4*)(hpack + t * (DHID * BR));
    #pragma unroll
    for (int w = threadIdx.x; w < DHID * BR / 4; w += 512) {
        int cc = w >> 2, r0 = (w & 3) * 4;
        hp[w] = make_float4(sh[cc][r0], sh[cc][r0 + 1], sh[cc][r0 + 2], sh[cc][r0 + 3]);
    }
}

// ---------------- GEMM2: latent + trig -> rowpack [t][i][48]={l16|a16|b16} ----------------
__global__ __launch_bounds__(1024) void gemm2_kernel(
    const float* __restrict__ W2T, const float* __restrict__ b2,
    const float* __restrict__ hpack, float4* __restrict__ rowpack, float* __restrict__ ln2s)
{
    __shared__ float part[8][DLAT][17];    // 69632 B
    __shared__ float tbuf[DLAT][49];       // 25088 B transpose buffer
    __shared__ float l2red[16][2];

    const int t = blockIdx.x;
    const int j = threadIdx.x & (DLAT - 1);
    const int g = __builtin_amdgcn_readfirstlane(threadIdx.x >> 7);   // wave-uniform
    const float* __restrict__ hrow = hpack + t * (DHID * BR);

    v2f acc[8];
    #pragma unroll
    for (int q = 0; q < 8; q++) acc[q] = (v2f)(0.f);

    for (int kk = 0; kk < 64; kk++) {
        int k = g * 64 + kk;
        float w = W2T[k * DLAT + j];
        v2f wv = {w, w};
        const float* hk = hrow + k * BR;               // uniform -> s_load_dwordx16
        #pragma unroll
        for (int q = 0; q < 8; q++) {
            v2f hv = {hk[2 * q], hk[2 * q + 1]};
            acc[q] = __builtin_elementwise_fma(hv, wv, acc[q]);
        }
    }
    #pragma unroll
    for (int q = 0; q < 8; q++) {
        part[g][j][2 * q]     = acc[q].x;
        part[g][j][2 * q + 1] = acc[q].y;
    }
    __syncthreads();

    const int rp = g;                                   // row-pair 0..7
    float s0 = 0.f, s1 = 0.f;
    #pragma unroll
    for (int g2 = 0; g2 < 8; g2++) {
        s0 += part[g2][j][2 * rp];
        s1 += part[g2][j][2 * rp + 1];
    }
    float bb = b2[j];
    float l0 = s0 + bb, l1 = s1 + bb;

    tbuf[j][2 * rp]          = l0;
    tbuf[j][2 * rp + 1]      = l1;
    tbuf[j][16 + 2 * rp]     = cosf(0.5f * l0);
    tbuf[j][16 + 2 * rp + 1] = cosf(0.5f * l1);
    tbuf[j][32 + 2 * rp]     = sinf(0.5f * l0);
    tbuf[j][32 + 2 * rp + 1] = sinf(0.5f * l1);

    // ||l||^2 per row
    const int wv = threadIdx.x >> 6;
    float v0 = l0 * l0, v1 = l1 * l1;
    for (int off = 32; off; off >>= 1) { v0 += __shfl_down(v0, off); v1 += __shfl_down(v1, off); }
    if ((threadIdx.x & 63) == 0) { l2red[wv][0] = v0; l2red[wv][1] = v1; }
    __syncthreads();

    if (threadIdx.x < BR) {
        int r = threadIdx.x, p = r >> 1, sel = r & 1;
        ln2s[t * BR + r] = l2red[2 * p][sel] + l2red[2 * p + 1][sel];
    }
    // coalesced rowpack store: 128*48 floats = 1536 float4 per tile
    for (int w = threadIdx.x; w < DLAT * 48 / 4; w += 1024) {
        int i = w / 12, off = (w % 12) * 4;
        rowpack[t * 1536 + w] = make_float4(tbuf[i][off], tbuf[i][off + 1],
                                            tbuf[i][off + 2], tbuf[i][off + 3]);
    }
}

// ---------------- stage B: 4 consecutive sups x 4 rows per lane, planar loads ----------------
// grid 256 x 512 (8 waves). wave = (row-quad rq = wv&3, sup-half sh = wv>>2).
// lane owns sups { sh*256 + lane*4 + k, k<4 } x rows { rq*4 .. rq*4+3 }.
__global__ __launch_bounds__(512, 2) void kernelB(
    const float* __restrict__ scS, const float* __restrict__ scC, const float* __restrict__ scN,
    const float* __restrict__ sn2, const float* __restrict__ wts,
    const float4* __restrict__ rowpack4, const float* __restrict__ ln2s,
    float* __restrict__ out)
{
    __shared__ float tile[DLAT * 48];   // 24 KB: [i][ l16 | a16 | b16 ]
    __shared__ float redw[8][4];

    const int t    = blockIdx.x;
    const int tid  = threadIdx.x;
    const int lane = tid & 63;
    const int wv   = __builtin_amdgcn_readfirstlane(tid >> 6);
    const int rq   = wv & 3;
    const int sh   = wv >> 2;
    const int s0   = sh * 256 + lane * 4;     // 4 consecutive supports per lane

    // ---- stage rowpack tile: 1536 float4, coalesced ----
    {
        const float4* src = rowpack4 + t * 1536;
        float4* dst = (float4*)tile;
        #pragma unroll
        for (int k = 0; k < 3; k++) dst[tid + k * 512] = src[tid + k * 512];
    }
    __syncthreads();

    v2f dot[4][2], prod[4][2];
    #pragma unroll
    for (int r = 0; r < 4; r++) {
        dot[r][0] = (v2f)(0.f);  dot[r][1] = (v2f)(0.f);
        prod[r][0] = (v2f)(1.f); prod[r][1] = (v2f)(1.f);
    }

    const float* pS = scS + s0;
    const float* pC = scC + s0;
    const float* pN = scN + s0;

    #pragma unroll 2
    for (int i = 0; i < DLAT; i++) {
        // per-lane coalesced planar loads: 3 x float4 (4 consecutive sups)
        float4 s4 = *(const float4*)(pS + i * NSUP);
        float4 c4 = *(const float4*)(pC + i * NSUP);
        float4 n4 = *(const float4*)(pN + i * NSUP);
        v2f s01 = {s4.x, s4.y}, s23 = {s4.z, s4.w};
        v2f c01 = {c4.x, c4.y}, c23 = {c4.z, c4.w};
        v2f n01 = {n4.x, n4.y}, n23 = {n4.z, n4.w};
        // broadcast row data (4 rows of this wave's quad) from LDS
        const float* tp = tile + i * 48 + rq * 4;
        float4 lq = *(const float4*)(tp);
        float4 aq = *(const float4*)(tp + 16);
        float4 bq = *(const float4*)(tp + 32);
        float lr[4] = {lq.x, lq.y, lq.z, lq.w};
        float ar[4] = {aq.x, aq.y, aq.z, aq.w};
        float br[4] = {bq.x, bq.y, bq.z, bq.w};
        #pragma unroll
        for (int r = 0; r < 4; r++) {
            v2f lb = {lr[r], lr[r]};
            v2f ab = {ar[r], ar[r]};
            v2f bb = {br[r], br[r]};
            dot[r][0] = __builtin_elementwise_fma(s01, lb, dot[r][0]);
            dot[r][1] = __builtin_elementwise_fma(s23, lb, dot[r][1]);
            v2f t0 = __builtin_elementwise_fma(c01, ab, n01 * bb);
            v2f t1 = __builtin_elementwise_fma(c23, ab, n23 * bb);
            prod[r][0] = prod[r][0] * t0;
            prod[r][1] = prod[r][1] * t1;
        }
    }

    // ---- epilogue: kernels, weight, reduce ----
    float4 snq = *(const float4*)(sn2 + s0);
    float4 wq  = *(const float4*)(wts + s0);
    float sn[4] = {snq.x, snq.y, snq.z, snq.w};
    float wk[4] = {wq.x,  wq.y,  wq.z,  wq.w};
    const float* lrp = ln2s + t * BR + rq * 4;       // wave-uniform, tiny
    float l2[4] = {lrp[0], lrp[1], lrp[2], lrp[3]};

    float rowacc[4];
    #pragma unroll
    for (int r = 0; r < 4; r++) {
        float d[4] = {dot[r][0].x, dot[r][0].y, dot[r][1].x, dot[r][1].y};
        float p[4] = {prod[r][0].x, prod[r][0].y, prod[r][1].x, prod[r][1].y};
        float acc = 0.f;
        #pragma unroll
        for (int k = 0; k < 4; k++) {
            float sq = l2[r] + sn[k] - 2.f * d[k];
            acc += (0.5f * __expf(-sq) + 0.5f * (p[k] * p[k])) * wk[k];
        }
        rowacc[r] = acc;
    }
    #pragma unroll
    for (int j = 0; j < 4; j++) {
        float v = rowacc[j];
        for (int off = 32; off; off >>= 1) v += __shfl_down(v, off);
        if (lane == 0) redw[wv][j] = v;
    }
    __syncthreads();
    if (tid < BR) {
        int q = tid >> 2, j = tid & 3;               // row = q*4 + j
        out[t * BR + q * 4 + j] = redw[q][j] + redw[4 + q][j];
    }
}

// ---------------- launch ----------------
extern "C" void kernel_launch(void* const* d_in, const int* in_sizes, int n_in,
                              void* d_out, int out_size, void* d_ws, size_t ws_size,
                              hipStream_t stream) {
    const float* x       = (const float*)d_in[0];
    const float* W1      = (const float*)d_in[1];
    const float* b1      = (const float*)d_in[2];
    const float* W2      = (const float*)d_in[3];
    const float* b2      = (const float*)d_in[4];
    const float* support = (const float*)d_in[5];
    const float* wts     = (const float*)d_in[6];
    float* out = (float*)d_out;

    float* ws      = (float*)d_ws;
    float* W1T     = ws;                        // 32768
    float* W2T     = W1T + 32768;               // 65536
    float* xpack   = W2T + 65536;               // 262144
    float* hpack   = xpack + 262144;            // 2097152   (16B-aligned offset)
    float* rowpack = hpack + 2097152;           // 1572864   (16B-aligned offset)
    float* ln2s    = rowpack + 1572864;         // 4096
    float* sn2     = ln2s + 4096;               // 512
    float* scS     = sn2 + 512;                 // 65536 (16B-aligned offset)
    float* scC     = scS + 65536;               // 65536
    float* scN     = scC + 65536;               // 65536

    prep_kernel <<<512,  512, 0, stream>>>(x, W1, W2, support, W1T, W2T, xpack,
                                           scS, scC, scN, sn2);
    gemm1_kernel<<<NTILE, 512, 0, stream>>>(W1T, b1, xpack, hpack);
    gemm2_kernel<<<NTILE, 1024, 0, stream>>>(W2T, b2, hpack, (float4*)rowpack, ln2s);
    kernelB     <<<NTILE, 512, 0, stream>>>(scS, scC, scN, sn2, wts,
                                            (const float4*)rowpack, ln2s, out);
}

// Round 8
// 84.253 us; speedup vs baseline: 1.0283x; 1.0283x over previous
//
#include <hip/hip_runtime.h>
#include <math.h>

typedef float v2f __attribute__((ext_vector_type(2)));

#define NSUP 512
#define DLAT 128
#define DHID 512
#define DIN  64
#define BR   16
#define NTILE 256   // 4096 / BR

// ---------------- prep: transposes + packs + planar support trig + norms ----------------
__global__ __launch_bounds__(512) void prep_kernel(
    const float* __restrict__ x, const float* __restrict__ W1, const float* __restrict__ W2,
    const float* __restrict__ support,
    float* __restrict__ W1T, float* __restrict__ W2T, float* __restrict__ xpack,
    float* __restrict__ scS, float* __restrict__ scC, float* __restrict__ scN,
    float* __restrict__ sn2)
{
    int idx = blockIdx.x * 512 + threadIdx.x;          // 512 x 512 = 262144
    {   // xpack[t][k][r] = x[t*16+r][k]   (writes coalesced)
        int t = idx >> 10, rem = idx & 1023, k = rem >> 4, r = rem & 15;
        xpack[idx] = x[((t << 4) | r) * DIN + k];
    }
    if (idx < DHID * DIN) {                 // W1 [512][64] -> W1T [64][512]
        int c = idx / DIN, k = idx % DIN;
        W1T[k * DHID + c] = W1[idx];
    }
    if (idx < DLAT * DHID) {
        int j = idx / DHID, k = idx % DHID;             // W2 -> W2T
        W2T[k * DLAT + j] = W2[idx];
        int s = idx & (NSUP - 1), i = idx >> 9;         // planar [i][s], writes coalesced
        float v = support[s * DLAT + i];
        scS[idx] = v;
        scC[idx] = cosf(0.5f * v);
        scN[idx] = sinf(0.5f * v);
    }
    if (idx < NSUP) {                       // ||s||^2 via float4
        const float4* sp = (const float4*)(support + idx * DLAT);
        float acc = 0.f;
        #pragma unroll 8
        for (int i4 = 0; i4 < DLAT / 4; i4++) {
            float4 v = sp[i4];
            acc = fmaf(v.x, v.x, fmaf(v.y, v.y, fmaf(v.z, v.z, fmaf(v.w, v.w, acc))));
        }
        sn2[idx] = acc;
    }
}

// ---------------- GEMM1: h = tanh(x @ W1^T + b1)  (s_load broadcast path) ----------------
__global__ __launch_bounds__(512) void gemm1_kernel(
    const float* __restrict__ W1T, const float* __restrict__ b1,
    const float* __restrict__ xpack, float* __restrict__ hpack)
{
    __shared__ float sh[DHID][17];                           // 34.8 KB
    const int t = blockIdx.x;
    const int c = threadIdx.x;
    const float* __restrict__ xr = xpack + t * (DIN * BR);   // uniform base -> s_load

    v2f acc[8];
    #pragma unroll
    for (int q = 0; q < 8; q++) acc[q] = (v2f)(0.f);

    for (int k = 0; k < DIN; k++) {
        float w = W1T[k * DHID + c];
        v2f wv = {w, w};
        const float* xk = xr + k * BR;                       // uniform -> s_load_dwordx16
        #pragma unroll
        for (int q = 0; q < 8; q++) {
            v2f xv = {xk[2 * q], xk[2 * q + 1]};
            acc[q] = __builtin_elementwise_fma(xv, wv, acc[q]);
        }
    }
    float bb = b1[c];
    #pragma unroll
    for (int q = 0; q < 8; q++) {
        sh[c][2 * q]     = tanhf(acc[q].x + bb);
        sh[c][2 * q + 1] = tanhf(acc[q].y + bb);
    }
    __syncthreads();
    float4* hp = (float4*)(hpack + t * (DHID * BR));
    #pragma unroll
    for (int w = threadIdx.x; w < DHID * BR / 4; w += 512) {
        int cc = w >> 2, r0 = (w & 3) * 4;
        hp[w] = make_float4(sh[cc][r0], sh[cc][r0 + 1], sh[cc][r0 + 2], sh[cc][r0 + 3]);
    }
}

// ---------------- GEMM2: latent + trig -> rowpack [t][i][48]={l16|a16|b16} ----------------
__global__ __launch_bounds__(1024) void gemm2_kernel(
    const float* __restrict__ W2T, const float* __restrict__ b2,
    const float* __restrict__ hpack, float4* __restrict__ rowpack, float* __restrict__ ln2s)
{
    __shared__ float part[8][DLAT][17];    // 69632 B
    __shared__ float tbuf[DLAT][49];       // 25088 B transpose buffer
    __shared__ float l2red[16][2];

    const int t = blockIdx.x;
    const int j = threadIdx.x & (DLAT - 1);
    const int g = __builtin_amdgcn_readfirstlane(threadIdx.x >> 7);   // wave-uniform
    const float* __restrict__ hrow = hpack + t * (DHID * BR);

    v2f acc[8];
    #pragma unroll
    for (int q = 0; q < 8; q++) acc[q] = (v2f)(0.f);

    for (int kk = 0; kk < 64; kk++) {
        int k = g * 64 + kk;
        float w = W2T[k * DLAT + j];
        v2f wv = {w, w};
        const float* hk = hrow + k * BR;               // uniform -> s_load_dwordx16
        #pragma unroll
        for (int q = 0; q < 8; q++) {
            v2f hv = {hk[2 * q], hk[2 * q + 1]};
            acc[q] = __builtin_elementwise_fma(hv, wv, acc[q]);
        }
    }
    #pragma unroll
    for (int q = 0; q < 8; q++) {
        part[g][j][2 * q]     = acc[q].x;
        part[g][j][2 * q + 1] = acc[q].y;
    }
    __syncthreads();

    const int rp = g;                                   // row-pair 0..7
    float s0 = 0.f, s1 = 0.f;
    #pragma unroll
    for (int g2 = 0; g2 < 8; g2++) {
        s0 += part[g2][j][2 * rp];
        s1 += part[g2][j][2 * rp + 1];
    }
    float bb = b2[j];
    float l0 = s0 + bb, l1 = s1 + bb;

    tbuf[j][2 * rp]          = l0;
    tbuf[j][2 * rp + 1]      = l1;
    tbuf[j][16 + 2 * rp]     = cosf(0.5f * l0);
    tbuf[j][16 + 2 * rp + 1] = cosf(0.5f * l1);
    tbuf[j][32 + 2 * rp]     = sinf(0.5f * l0);
    tbuf[j][32 + 2 * rp + 1] = sinf(0.5f * l1);

    // ||l||^2 per row
    const int wv = threadIdx.x >> 6;
    float v0 = l0 * l0, v1 = l1 * l1;
    for (int off = 32; off; off >>= 1) { v0 += __shfl_down(v0, off); v1 += __shfl_down(v1, off); }
    if ((threadIdx.x & 63) == 0) { l2red[wv][0] = v0; l2red[wv][1] = v1; }
    __syncthreads();

    if (threadIdx.x < BR) {
        int r = threadIdx.x, p = r >> 1, sel = r & 1;
        ln2s[t * BR + r] = l2red[2 * p][sel] + l2red[2 * p + 1][sel];
    }
    // coalesced rowpack store: 128*48 floats = 1536 float4 per tile
    for (int w = threadIdx.x; w < DLAT * 48 / 4; w += 1024) {
        int i = w / 12, off = (w % 12) * 4;
        rowpack[t * 1536 + w] = make_float4(tbuf[i][off], tbuf[i][off + 1],
                                            tbuf[i][off + 2], tbuf[i][off + 3]);
    }
}

// ---------------- stage B: grid (t, sup-quarter), 1 sup x 4 rows per lane ----------------
// grid 1024 = 256 t x 4 sq. block 512 thr (8 waves), 4 blocks/CU -> 32 waves/CU.
// wave w: rq = w&3 (rows rq*4..rq*4+3), sg = w>>2; lane sup s = sq*128 + sg*64 + lane.
__global__ __launch_bounds__(512, 8) void kernelB(
    const float* __restrict__ scS, const float* __restrict__ scC, const float* __restrict__ scN,
    const float* __restrict__ sn2, const float* __restrict__ wts,
    const float4* __restrict__ rowpack4, const float* __restrict__ ln2s,
    float* __restrict__ outpart)
{
    __shared__ float tile[DLAT * 48];   // 24 KB: [i][ l16 | a16 | b16 ]
    __shared__ float redw[8][4];

    const int b    = blockIdx.x;
    const int t    = b >> 2;
    const int sq   = b & 3;
    const int tid  = threadIdx.x;
    const int lane = tid & 63;
    const int wv   = __builtin_amdgcn_readfirstlane(tid >> 6);
    const int rq   = wv & 3;
    const int sg   = wv >> 2;
    const int s    = sq * 128 + sg * 64 + lane;       // one support per lane

    // ---- stage rowpack tile: 1536 float4, coalesced ----
    {
        const float4* src = rowpack4 + t * 1536;
        float4* dst = (float4*)tile;
        #pragma unroll
        for (int k = 0; k < 3; k++) dst[tid + k * 512] = src[tid + k * 512];
    }
    __syncthreads();

    v2f dot01 = (v2f)(0.f), dot23 = (v2f)(0.f);
    v2f prod01 = (v2f)(1.f), prod23 = (v2f)(1.f);

    const float* pS = scS + s;
    const float* pC = scC + s;
    const float* pN = scN + s;

    #pragma unroll 4
    for (int i = 0; i < DLAT; i++) {
        float sv = pS[i * NSUP];                      // per-lane, coalesced 256B/wave
        float cv = pC[i * NSUP];
        float nv = pN[i * NSUP];
        const float* tp = tile + i * 48 + rq * 4;     // wave-uniform -> LDS broadcast
        float4 lq = *(const float4*)(tp);
        float4 aq = *(const float4*)(tp + 16);
        float4 bq = *(const float4*)(tp + 32);
        v2f svv = {sv, sv}, cvv = {cv, cv}, nvv = {nv, nv};
        dot01 = __builtin_elementwise_fma((v2f){lq.x, lq.y}, svv, dot01);
        dot23 = __builtin_elementwise_fma((v2f){lq.z, lq.w}, svv, dot23);
        v2f t01 = __builtin_elementwise_fma((v2f){aq.x, aq.y}, cvv, (v2f){bq.x, bq.y} * nvv);
        v2f t23 = __builtin_elementwise_fma((v2f){aq.z, aq.w}, cvv, (v2f){bq.z, bq.w} * nvv);
        prod01 = prod01 * t01;
        prod23 = prod23 * t23;
    }

    // ---- epilogue: kernels, weight, per-row reduce over this block's 128 sups ----
    float sn  = sn2[s];
    float wgt = wts[s];
    const float* lrp = ln2s + t * BR + rq * 4;        // wave-uniform, tiny
    float l2[4] = {lrp[0], lrp[1], lrp[2], lrp[3]};
    float d[4] = {dot01.x, dot01.y, dot23.x, dot23.y};
    float p[4] = {prod01.x, prod01.y, prod23.x, prod23.y};

    float rowacc[4];
    #pragma unroll
    for (int r = 0; r < 4; r++) {
        float sq_ = l2[r] + sn - 2.f * d[r];
        rowacc[r] = (0.5f * __expf(-sq_) + 0.5f * (p[r] * p[r])) * wgt;
    }
    #pragma unroll
    for (int j = 0; j < 4; j++) {
        float v = rowacc[j];
        for (int off = 32; off; off >>= 1) v += __shfl_down(v, off);
        if (lane == 0) redw[wv][j] = v;
    }
    __syncthreads();
    if (tid < BR) {
        int q = tid >> 2, j = tid & 3;                // row = q*4 + j
        outpart[sq * (NTILE * BR) + t * BR + q * 4 + j] = redw[q][j] + redw[4 + q][j];
    }
}

// ---------------- combine: out = sum of 4 support-quarter partials ----------------
__global__ __launch_bounds__(256) void combine_kernel(
    const float* __restrict__ outpart, float* __restrict__ out)
{
    int i = blockIdx.x * 256 + threadIdx.x;           // 0..4095
    out[i] = (outpart[i] + outpart[NTILE * BR + i])
           + (outpart[2 * NTILE * BR + i] + outpart[3 * NTILE * BR + i]);
}

// ---------------- launch ----------------
extern "C" void kernel_launch(void* const* d_in, const int* in_sizes, int n_in,
                              void* d_out, int out_size, void* d_ws, size_t ws_size,
                              hipStream_t stream) {
    const float* x       = (const float*)d_in[0];
    const float* W1      = (const float*)d_in[1];
    const float* b1      = (const float*)d_in[2];
    const float* W2      = (const float*)d_in[3];
    const float* b2      = (const float*)d_in[4];
    const float* support = (const float*)d_in[5];
    const float* wts     = (const float*)d_in[6];
    float* out = (float*)d_out;

    float* ws      = (float*)d_ws;
    float* W1T     = ws;                        // 32768
    float* W2T     = W1T + 32768;               // 65536
    float* xpack   = W2T + 65536;               // 262144
    float* hpack   = xpack + 262144;            // 2097152   (16B-aligned offset)
    float* rowpack = hpack + 2097152;           // 1572864   (16B-aligned offset)
    float* ln2s    = rowpack + 1572864;         // 4096
    float* sn2     = ln2s + 4096;               // 512
    float* scS     = sn2 + 512;                 // 65536 (16B-aligned offset)
    float* scC     = scS + 65536;               // 65536
    float* scN     = scC + 65536;               // 65536
    float* outpart = scN + 65536;               // 16384

    prep_kernel <<<512,  512, 0, stream>>>(x, W1, W2, support, W1T, W2T, xpack,
                                           scS, scC, scN, sn2);
    gemm1_kernel<<<NTILE, 512, 0, stream>>>(W1T, b1, xpack, hpack);
    gemm2_kernel<<<NTILE, 1024, 0, stream>>>(W2T, b2, hpack, (float4*)rowpack, ln2s);
    kernelB     <<<NTILE * 4, 512, 0, stream>>>(scS, scC, scN, sn2, wts,
                                                (const float4*)rowpack, ln2s, outpart);
    combine_kernel<<<16, 256, 0, stream>>>(outpart, out);
}